// Round 6
// baseline (152.963 us; speedup 1.0000x reference)
//
#include <hip/hip_runtime.h>

typedef _Float16 f16;
typedef __attribute__((ext_vector_type(8))) f16 f16x8;
typedef __attribute__((ext_vector_type(4))) f16 f16x4;
typedef __attribute__((ext_vector_type(2))) __fp16 h16x2;   // cvt_pkrtz result type
typedef __attribute__((ext_vector_type(4))) float floatx4;

#define NPIX 4096
#define KT   128          // keys per attention tile
#define VROW 136          // padded LDS row (128 keys + 8) in f16

// ---------------------------------------------------------------------------
// Kernel 0: convert w_qkv (384x128) and w_proj (128x128) fp32 -> f16 once.
// Q rows (o<128) of w_qkv are pre-scaled by SCALE*log2(e) so attention can
// use exp2 with no per-element scale. 65536 floats total, 64 blocks x 256 x 4.
// ---------------------------------------------------------------------------
__global__ __launch_bounds__(256) void cvt_w(
    const float* __restrict__ wq, const float* __restrict__ wp,
    f16* __restrict__ wh, f16* __restrict__ wph)
{
    const int idx = (blockIdx.x * 256 + threadIdx.x) * 4;   // < 65536
    const float qs = 0.17677669529663687f * 1.4426950408889634f;
    float4 v;
    f16* dst;
    if (idx < 49152) { v = *(const float4*)(wq + idx); dst = wh + idx; }
    else             { v = *(const float4*)(wp + (idx - 49152)); dst = wph + (idx - 49152); }
    if (idx < 16384) { v.x *= qs; v.y *= qs; v.z *= qs; v.w *= qs; }  // Q rows
    h16x2 a = __builtin_amdgcn_cvt_pkrtz(v.x, v.y);
    h16x2 b = __builtin_amdgcn_cvt_pkrtz(v.z, v.w);
    f16x4 h; h[0] = (f16)a[0]; h[1] = (f16)a[1]; h[2] = (f16)b[0]; h[3] = (f16)b[1];
    *(f16x4*)dst = h;
}

// ---------------------------------------------------------------------------
// Kernel 1: QKV projection, LDS-free MFMA GEMM.
// grid (64 p-tiles, 4 b), block 256 (4 waves x 16 pixels).
// Key identity: the per-lane X gather for the A-role (X^T, Q/K path) and the
// B-role (X, V path) is IDENTICAL (element X[c=quad*8+j][p=l16]) -> gather
// once, use for all 6 o-tiles. W fragments are read straight from f16 global
// (each wave reads a dense, permuted 4KB row-block; L2-resident).
// ---------------------------------------------------------------------------
__global__ __launch_bounds__(256) void qkv_mfma(
    const float* __restrict__ x, const f16* __restrict__ wh,
    f16* __restrict__ qh, f16* __restrict__ kh, f16* __restrict__ vth)
{
    const int tid  = threadIdx.x;
    const int wave = tid >> 6;
    const int lane = tid & 63;
    const int quad = lane >> 4;
    const int l16  = lane & 15;
    const int pbase = blockIdx.x * 64;
    const int b     = blockIdx.y;
    const int p_col = pbase + wave * 16 + l16;

    const float* xb = x + (size_t)b * 128 * NPIX;

    // one X gather serves both A (Q/K) and B (V) fragment roles
    f16x8 xf[4];
#pragma unroll
    for (int kc = 0; kc < 4; ++kc) {
        const int c0 = kc * 32 + quad * 8;
        float e[8];
#pragma unroll
        for (int j = 0; j < 8; ++j)
            e[j] = xb[(size_t)(c0 + j) * NPIX + p_col];
#pragma unroll
        for (int j = 0; j < 4; ++j) {
            h16x2 pk = __builtin_amdgcn_cvt_pkrtz(e[2 * j], e[2 * j + 1]);
            xf[kc][2 * j] = (f16)pk[0]; xf[kc][2 * j + 1] = (f16)pk[1];
        }
    }

#pragma unroll
    for (int y = 0; y < 6; ++y) {
        floatx4 acc[4];
#pragma unroll
        for (int i = 0; i < 4; ++i) acc[i] = floatx4{0.f, 0.f, 0.f, 0.f};

        if (y < 4) {
            // C[p][o]: A = X^T (regs), B = W (global f16)
#pragma unroll
            for (int n = 0; n < 4; ++n)
#pragma unroll
                for (int kc = 0; kc < 4; ++kc) {
                    f16x8 wf = *(const f16x8*)&wh[(size_t)(y * 64 + n * 16 + l16) * 128 + kc * 32 + quad * 8];
                    acc[n] = __builtin_amdgcn_mfma_f32_16x16x32_f16(xf[kc], wf, acc[n], 0, 0, 0);
                }
            f16* dst = (y < 2) ? qh : kh;
#pragma unroll
            for (int n = 0; n < 4; ++n) {
                const int og    = y * 64 + n * 16 + l16;
                const int local = og & 127;
                const int head  = local >> 5;
                const int d     = local & 31;
                f16* base = dst + (size_t)(b * 4 + head) * NPIX * 32;
#pragma unroll
                for (int r = 0; r < 4; ++r) {
                    const int p = pbase + wave * 16 + quad * 4 + r;
                    base[(size_t)p * 32 + d] = (f16)acc[n][r];
                }
            }
        } else {
            // C[o][p]: A = W (global f16), B = X (regs)
#pragma unroll
            for (int m = 0; m < 4; ++m)
#pragma unroll
                for (int kc = 0; kc < 4; ++kc) {
                    f16x8 wf = *(const f16x8*)&wh[(size_t)(y * 64 + m * 16 + l16) * 128 + kc * 32 + quad * 8];
                    acc[m] = __builtin_amdgcn_mfma_f32_16x16x32_f16(wf, xf[kc], acc[m], 0, 0, 0);
                }
#pragma unroll
            for (int m = 0; m < 4; ++m)
#pragma unroll
                for (int r = 0; r < 4; ++r) {
                    const int ov   = (y - 4) * 64 + m * 16 + quad * 4 + r;
                    const int head = ov >> 5;
                    const int d    = ov & 31;
                    vth[((size_t)(b * 4 + head) * 32 + d) * NPIX + p_col] = (f16)acc[m][r];
                }
        }
    }
}

// ---------------------------------------------------------------------------
// Kernel 2: flash attention via S^T = K*Q^T, 16 q per wave, grid 1024 blocks
// (4 blocks/CU -> 16 waves/CU). Block index XCD-swizzled so each XCD works on
// 2 bh only (K/V L2-resident). PV uses K=32 MFMAs: the 32-key group order is
// defined as the concat of two 16-key C-layout tiles (PV is key-order
// invariant), so the A-frag is the in-lane concat of two exp tiles and the
// B-frag is two b64 reads from vlds.
// ---------------------------------------------------------------------------
__global__ __launch_bounds__(256, 4) void attn_kernel(
    const f16* __restrict__ qh, const f16* __restrict__ kh,
    const f16* __restrict__ vth, f16* __restrict__ att)
{
    __shared__ f16 klds[KT * 32];      // [key][d] 8 KB
    __shared__ f16 vlds[32 * VROW];    // [d][key] padded 8.5 KB

    const int tid  = threadIdx.x;
    const int wave = tid >> 6;
    const int lane = tid & 63;
    const int quad = lane >> 4;
    const int l16  = lane & 15;

    const int n    = blockIdx.x;               // 0..1023
    const int bh   = (n & 7) * 2 + ((n >> 3) & 1);
    const int qblk = n >> 4;                   // 0..63
    const int qbase = qblk * 64 + wave * 16;

    const f16* kb = kh + (size_t)bh * NPIX * 32;
    const f16* vb = vth + (size_t)bh * 32 * NPIX;

    // Q B-frag (B[k=d][n=q])
    f16x8 qB = *(const f16x8*)(qh + ((size_t)bh * NPIX + qbase + l16) * 32 + quad * 8);

    floatx4 oacc[2];
    oacc[0] = floatx4{0.f, 0.f, 0.f, 0.f};
    oacc[1] = floatx4{0.f, 0.f, 0.f, 0.f};
    float lsum = 0.f;

    for (int kt = 0; kt < NPIX / KT; ++kt) {
        __syncthreads();
        {   // stage K tile: 128 keys x 32 d = 8 KB contiguous
            const int4* src = (const int4*)(kb + (size_t)kt * KT * 32);
            ((int4*)klds)[tid]       = src[tid];
            ((int4*)klds)[tid + 256] = src[tid + 256];
        }
        {   // stage V tile: 32 d-rows x 128 keys into padded rows
            const int r  = tid >> 3;
            const int cc = (tid & 7) * 2;
            const int4* vsrc = (const int4*)(vb + (size_t)r * NPIX + kt * KT + cc * 8);
            int4 v0 = vsrc[0], v1 = vsrc[1];
            int4* vdst = (int4*)(vlds + r * VROW + cc * 8);
            vdst[0] = v0; vdst[1] = v1;
        }
        __syncthreads();

        // S^T: 8 tiles of 16 keys, K=32 full reduction
        floatx4 st[8];
#pragma unroll
        for (int t = 0; t < 8; ++t) {
            f16x8 kf = *(const f16x8*)&klds[(t * 16 + l16) * 32 + quad * 8];
            floatx4 z = {0.f, 0.f, 0.f, 0.f};
            st[t] = __builtin_amdgcn_mfma_f32_16x16x32_f16(kf, qB, z, 0, 0, 0);
        }

        // softmax numerator: exp2 + pack (pkrtz) in-lane -> P A-frag quarters
        f16x4 paf[8];
#pragma unroll
        for (int t = 0; t < 8; ++t) {
            float e0 = __builtin_amdgcn_exp2f(st[t][0]);
            float e1 = __builtin_amdgcn_exp2f(st[t][1]);
            float e2 = __builtin_amdgcn_exp2f(st[t][2]);
            float e3 = __builtin_amdgcn_exp2f(st[t][3]);
            lsum += (e0 + e1) + (e2 + e3);
            h16x2 lo = __builtin_amdgcn_cvt_pkrtz(e0, e1);
            h16x2 hi = __builtin_amdgcn_cvt_pkrtz(e2, e3);
            paf[t][0] = (f16)lo[0]; paf[t][1] = (f16)lo[1];
            paf[t][2] = (f16)hi[0]; paf[t][3] = (f16)hi[1];
        }

        // PV: K=32 over permuted key-groups (tiles 2g, 2g+1)
#pragma unroll
        for (int g = 0; g < 4; ++g) {
            f16x8 pA;
#pragma unroll
            for (int j = 0; j < 4; ++j) { pA[j] = paf[2 * g][j]; pA[4 + j] = paf[2 * g + 1][j]; }
#pragma unroll
            for (int dh = 0; dh < 2; ++dh) {
                const f16* vrow = &vlds[(dh * 16 + l16) * VROW + 32 * g + quad * 4];
                f16x4 v0 = *(const f16x4*)(vrow);
                f16x4 v1 = *(const f16x4*)(vrow + 16);
                f16x8 vB;
#pragma unroll
                for (int j = 0; j < 4; ++j) { vB[j] = v0[j]; vB[4 + j] = v1[j]; }
                oacc[dh] = __builtin_amdgcn_mfma_f32_16x16x32_f16(pA, vB, oacc[dh], 0, 0, 0);
            }
        }
    }

    // epilogue: reduce lsum across quads (q = l16), divide, store f16
    float l = lsum;
    l += __shfl_xor(l, 16);
    l += __shfl_xor(l, 32);
    const float inv = 1.0f / l;                 // sum for q = l16
#pragma unroll
    for (int r = 0; r < 4; ++r) {
        const float invr = __shfl(inv, quad * 4 + r);   // inv for q-row quad*4+r
        const int q = qbase + quad * 4 + r;
        f16* ob = att + ((size_t)bh * NPIX + q) * 32;
        ob[l16]      = (f16)(oacc[0][r] * invr);
        ob[16 + l16] = (f16)(oacc[1][r] * invr);
    }
}

// ---------------------------------------------------------------------------
// Kernel 3: output projection, LDS-free MFMA GEMM.
// C[o][p] = Wp[o][c] * att^T[c][p] + bias; att[bh][p][32] is the natural
// B-frag layout; Wp A-frags straight from f16 global. grid (64 p-tiles, 4 b).
// ---------------------------------------------------------------------------
__global__ __launch_bounds__(256) void proj_mfma(
    const f16* __restrict__ att, const f16* __restrict__ wph,
    const float* __restrict__ bp, float* __restrict__ out)
{
    const int tid  = threadIdx.x;
    const int wave = tid >> 6;
    const int lane = tid & 63;
    const int quad = lane >> 4;
    const int l16  = lane & 15;
    const int pbase = blockIdx.x * 64;
    const int b     = blockIdx.y;
    const int p_col = pbase + wave * 16 + l16;

    const f16* ab = att + (size_t)b * 4 * NPIX * 32;
    f16x8 bf[4];
#pragma unroll
    for (int kc = 0; kc < 4; ++kc)
        bf[kc] = *(const f16x8*)(ab + ((size_t)kc * NPIX + p_col) * 32 + quad * 8);

    floatx4 acc[8];
#pragma unroll
    for (int m = 0; m < 8; ++m) acc[m] = floatx4{0.f, 0.f, 0.f, 0.f};
#pragma unroll
    for (int m = 0; m < 8; ++m)
#pragma unroll
        for (int kc = 0; kc < 4; ++kc) {
            f16x8 af = *(const f16x8*)&wph[(size_t)(m * 16 + l16) * 128 + kc * 32 + quad * 8];
            acc[m] = __builtin_amdgcn_mfma_f32_16x16x32_f16(af, bf[kc], acc[m], 0, 0, 0);
        }

#pragma unroll
    for (int m = 0; m < 8; ++m)
#pragma unroll
        for (int r = 0; r < 4; ++r) {
            const int o = m * 16 + quad * 4 + r;
            out[((size_t)b * 128 + o) * NPIX + p_col] = acc[m][r] + bp[o];
        }
}

// ---------------------------------------------------------------------------
extern "C" void kernel_launch(void* const* d_in, const int* in_sizes, int n_in,
                              void* d_out, int out_size, void* d_ws, size_t ws_size,
                              hipStream_t stream)
{
    const float* x      = (const float*)d_in[0];
    const float* w_qkv  = (const float*)d_in[1];
    const float* w_proj = (const float*)d_in[2];
    const float* b_proj = (const float*)d_in[3];
    float* out = (float*)d_out;

    char* ws = (char*)d_ws;
    f16* qh  = (f16*)(ws);                         // 4 MB [bh][p][32], pre-scaled
    f16* kh  = (f16*)(ws + (4u << 20));            // 4 MB [bh][p][32]
    f16* vth = (f16*)(ws + (8u << 20));            // 4 MB [bh][d][p]
    f16* att = (f16*)(ws + (12u << 20));           // 4 MB [bh][p][32]
    f16* wh  = (f16*)(ws + (16u << 20));           // 96 KB f16 w_qkv (Q rows scaled)
    f16* wph = (f16*)(ws + (16u << 20) + (96u << 10)); // 32 KB f16 w_proj

    cvt_w<<<dim3(64, 1, 1), 256, 0, stream>>>(w_qkv, w_proj, wh, wph);
    qkv_mfma<<<dim3(64, 4, 1), 256, 0, stream>>>(x, wh, qh, kh, vth);
    attn_kernel<<<dim3(1024, 1, 1), 256, 0, stream>>>(qh, kh, vth, att);
    proj_mfma<<<dim3(64, 4, 1), 256, 0, stream>>>(att, wph, b_proj, out);
}

// Round 7
// 141.451 us; speedup vs baseline: 1.0814x; 1.0814x over previous
//
#include <hip/hip_runtime.h>

typedef _Float16 f16;
typedef __attribute__((ext_vector_type(8))) f16 f16x8;
typedef __attribute__((ext_vector_type(4))) f16 f16x4;
typedef __attribute__((ext_vector_type(2))) __fp16 h16x2;   // cvt_pkrtz result type
typedef __attribute__((ext_vector_type(4))) float floatx4;

#define NPIX 4096
#define KT   128          // keys per attention tile
#define VROW 136          // padded LDS row (128 keys + 8) in f16

// ---------------------------------------------------------------------------
// Kernel 0: convert w_qkv (384x128) and w_proj (128x128) fp32 -> f16 once.
// Q rows (o<128) of w_qkv pre-scaled by SCALE*log2(e).
// ---------------------------------------------------------------------------
__global__ __launch_bounds__(256) void cvt_w(
    const float* __restrict__ wq, const float* __restrict__ wp,
    f16* __restrict__ wh, f16* __restrict__ wph)
{
    const int idx = (blockIdx.x * 256 + threadIdx.x) * 4;   // < 65536
    const float qs = 0.17677669529663687f * 1.4426950408889634f;
    float4 v;
    f16* dst;
    if (idx < 49152) { v = *(const float4*)(wq + idx); dst = wh + idx; }
    else             { v = *(const float4*)(wp + (idx - 49152)); dst = wph + (idx - 49152); }
    if (idx < 16384) { v.x *= qs; v.y *= qs; v.z *= qs; v.w *= qs; }  // Q rows
    h16x2 a = __builtin_amdgcn_cvt_pkrtz(v.x, v.y);
    h16x2 b = __builtin_amdgcn_cvt_pkrtz(v.z, v.w);
    f16x4 h; h[0] = (f16)a[0]; h[1] = (f16)a[1]; h[2] = (f16)b[0]; h[3] = (f16)b[1];
    *(f16x4*)dst = h;
}

// ---------------------------------------------------------------------------
// Kernel 1: QKV projection, LDS-free MFMA GEMM, o-tile split across blocks.
// grid (64 p-tiles, 6 y, 4 b) = 1536 blocks (6/CU). Each block: 64 p, one
// 64-o tile. X gather (per-lane 8 channels of 1 pixel) serves both A-role
// (Q/K: C[p][o]) and B-role (V: C[o][p]). W frags straight from f16 global.
// ---------------------------------------------------------------------------
__global__ __launch_bounds__(256) void qkv_mfma(
    const float* __restrict__ x, const f16* __restrict__ wh,
    f16* __restrict__ qh, f16* __restrict__ kh, f16* __restrict__ vth)
{
    const int tid  = threadIdx.x;
    const int wave = tid >> 6;
    const int lane = tid & 63;
    const int quad = lane >> 4;
    const int l16  = lane & 15;
    const int pbase = blockIdx.x * 64;
    const int y     = blockIdx.y;      // o-tile of 64; 0-1=q, 2-3=k, 4-5=v
    const int b     = blockIdx.z;
    const int p_col = pbase + wave * 16 + l16;

    const float* xb = x + (size_t)b * 128 * NPIX;

    f16x8 xf[4];
#pragma unroll
    for (int kc = 0; kc < 4; ++kc) {
        const int c0 = kc * 32 + quad * 8;
        float e[8];
#pragma unroll
        for (int j = 0; j < 8; ++j)
            e[j] = xb[(size_t)(c0 + j) * NPIX + p_col];
#pragma unroll
        for (int j = 0; j < 4; ++j) {
            h16x2 pk = __builtin_amdgcn_cvt_pkrtz(e[2 * j], e[2 * j + 1]);
            xf[kc][2 * j] = (f16)pk[0]; xf[kc][2 * j + 1] = (f16)pk[1];
        }
    }

    floatx4 acc[4];
#pragma unroll
    for (int i = 0; i < 4; ++i) acc[i] = floatx4{0.f, 0.f, 0.f, 0.f};

    if (y < 4) {
        // C[p][o]: A = X^T (regs), B = W (global f16)
#pragma unroll
        for (int n = 0; n < 4; ++n)
#pragma unroll
            for (int kc = 0; kc < 4; ++kc) {
                f16x8 wf = *(const f16x8*)&wh[(size_t)(y * 64 + n * 16 + l16) * 128 + kc * 32 + quad * 8];
                acc[n] = __builtin_amdgcn_mfma_f32_16x16x32_f16(xf[kc], wf, acc[n], 0, 0, 0);
            }
        f16* dst = (y < 2) ? qh : kh;
#pragma unroll
        for (int n = 0; n < 4; ++n) {
            const int og    = y * 64 + n * 16 + l16;
            const int local = og & 127;
            const int head  = local >> 5;
            const int d     = local & 31;
            f16* base = dst + (size_t)(b * 4 + head) * NPIX * 32;
#pragma unroll
            for (int r = 0; r < 4; ++r) {
                const int p = pbase + wave * 16 + quad * 4 + r;
                base[(size_t)p * 32 + d] = (f16)acc[n][r];
            }
        }
    } else {
        // C[o][p]: A = W (global f16), B = X (regs)
#pragma unroll
        for (int m = 0; m < 4; ++m)
#pragma unroll
            for (int kc = 0; kc < 4; ++kc) {
                f16x8 wf = *(const f16x8*)&wh[(size_t)(y * 64 + m * 16 + l16) * 128 + kc * 32 + quad * 8];
                acc[m] = __builtin_amdgcn_mfma_f32_16x16x32_f16(wf, xf[kc], acc[m], 0, 0, 0);
            }
#pragma unroll
        for (int m = 0; m < 4; ++m)
#pragma unroll
            for (int r = 0; r < 4; ++r) {
                const int ov   = (y - 4) * 64 + m * 16 + quad * 4 + r;
                const int head = ov >> 5;
                const int d    = ov & 31;
                vth[((size_t)(b * 4 + head) * 32 + d) * NPIX + p_col] = (f16)acc[m][r];
            }
    }
}

// ---------------------------------------------------------------------------
// Kernel 2: flash attention via S^T = K*Q^T, split-K 2-way.
// 32 q/wave (128 q/block, R4 amortization), grid 1024 = 4 blocks/CU.
// Fixed-max softmax makes split-K trivial: unnormalized O and l just add.
// bh XCD-swizzled (each XCD sees 2 bh -> K/V L2-resident, R6-verified).
// PV uses K=32 MFMAs via in-lane concat of two 16-key C-layout tiles.
// Partials: O -> f16 po[split][bh][q][32], l -> fp32 pl[split][bh*4096+q].
// ---------------------------------------------------------------------------
__global__ __launch_bounds__(256, 4) void attn_kernel(
    const f16* __restrict__ qh, const f16* __restrict__ kh,
    const f16* __restrict__ vth, f16* __restrict__ po, float* __restrict__ pl)
{
    __shared__ f16 klds[KT * 32];      // [key][d] 8 KB
    __shared__ f16 vlds[32 * VROW];    // [d][key] padded 8.5 KB

    const int tid  = threadIdx.x;
    const int wave = tid >> 6;
    const int lane = tid & 63;
    const int quad = lane >> 4;
    const int l16  = lane & 15;

    const int n     = blockIdx.x;              // 0..1023
    const int bh    = (n & 7) * 2 + ((n >> 3) & 1);
    const int qblk  = (n >> 4) & 31;           // 0..31 (128 q each)
    const int split = n >> 9;                  // 0..1 (2048 keys each)
    const int qbase = qblk * 128 + wave * 32;

    const f16* kb = kh + (size_t)bh * NPIX * 32;
    const f16* vb = vth + (size_t)bh * 32 * NPIX;

    // Q B-frags (B[k=d][n=q]) for two 16-q subtiles
    f16x8 qB[2];
#pragma unroll
    for (int h = 0; h < 2; ++h)
        qB[h] = *(const f16x8*)(qh + ((size_t)bh * NPIX + qbase + h * 16 + l16) * 32 + quad * 8);

    floatx4 oacc[2][2];
#pragma unroll
    for (int h = 0; h < 2; ++h)
#pragma unroll
        for (int dh = 0; dh < 2; ++dh) oacc[h][dh] = floatx4{0.f, 0.f, 0.f, 0.f};
    float lsum[2] = {0.f, 0.f};

    for (int kt = split * 16; kt < split * 16 + 16; ++kt) {
        __syncthreads();
        {   // stage K tile: 128 keys x 32 d = 8 KB contiguous
            const int4* src = (const int4*)(kb + (size_t)kt * KT * 32);
            ((int4*)klds)[tid]       = src[tid];
            ((int4*)klds)[tid + 256] = src[tid + 256];
        }
        {   // stage V tile: 32 d-rows x 128 keys into padded rows
            const int r  = tid >> 3;
            const int cc = (tid & 7) * 2;
            const int4* vsrc = (const int4*)(vb + (size_t)r * NPIX + kt * KT + cc * 8);
            int4 v0 = vsrc[0], v1 = vsrc[1];
            int4* vdst = (int4*)(vlds + r * VROW + cc * 8);
            vdst[0] = v0; vdst[1] = v1;
        }
        __syncthreads();

        // K A-frags shared across both h subtiles
        f16x8 kf[8];
#pragma unroll
        for (int t = 0; t < 8; ++t)
            kf[t] = *(const f16x8*)&klds[(t * 16 + l16) * 32 + quad * 8];

#pragma unroll
        for (int h = 0; h < 2; ++h) {
            floatx4 st[8];
#pragma unroll
            for (int t = 0; t < 8; ++t) {
                floatx4 z = {0.f, 0.f, 0.f, 0.f};
                st[t] = __builtin_amdgcn_mfma_f32_16x16x32_f16(kf[t], qB[h], z, 0, 0, 0);
            }
            f16x4 paf[8];
            float ls = 0.f;
#pragma unroll
            for (int t = 0; t < 8; ++t) {
                float e0 = __builtin_amdgcn_exp2f(st[t][0]);
                float e1 = __builtin_amdgcn_exp2f(st[t][1]);
                float e2 = __builtin_amdgcn_exp2f(st[t][2]);
                float e3 = __builtin_amdgcn_exp2f(st[t][3]);
                ls += (e0 + e1) + (e2 + e3);
                h16x2 lo = __builtin_amdgcn_cvt_pkrtz(e0, e1);
                h16x2 hi = __builtin_amdgcn_cvt_pkrtz(e2, e3);
                paf[t][0] = (f16)lo[0]; paf[t][1] = (f16)lo[1];
                paf[t][2] = (f16)hi[0]; paf[t][3] = (f16)hi[1];
            }
            lsum[h] += ls;
            // PV: K=32 over concat key-groups (tiles 2g, 2g+1)
#pragma unroll
            for (int g = 0; g < 4; ++g) {
                f16x8 pA;
#pragma unroll
                for (int j = 0; j < 4; ++j) { pA[j] = paf[2 * g][j]; pA[4 + j] = paf[2 * g + 1][j]; }
#pragma unroll
                for (int dh = 0; dh < 2; ++dh) {
                    const f16* vrow = &vlds[(dh * 16 + l16) * VROW + 32 * g + quad * 4];
                    f16x4 v0 = *(const f16x4*)(vrow);
                    f16x4 v1 = *(const f16x4*)(vrow + 16);
                    f16x8 vB;
#pragma unroll
                    for (int j = 0; j < 4; ++j) { vB[j] = v0[j]; vB[4 + j] = v1[j]; }
                    oacc[h][dh] = __builtin_amdgcn_mfma_f32_16x16x32_f16(pA, vB, oacc[h][dh], 0, 0, 0);
                }
            }
        }
    }

    // epilogue: store unnormalized partials
    const size_t bq = (size_t)(split * 16 + bh) * NPIX;
#pragma unroll
    for (int h = 0; h < 2; ++h) {
        float l = lsum[h];
        l += __shfl_xor(l, 16);
        l += __shfl_xor(l, 32);
        if (quad == 0)
            pl[bq + qbase + h * 16 + l16] = l;   // per-q sum held at lane l16
        f16* poh = po + (bq + qbase + h * 16) * 32;
#pragma unroll
        for (int r = 0; r < 4; ++r) {
            poh[(quad * 4 + r) * 32 + l16]      = (f16)oacc[h][0][r];
            poh[(quad * 4 + r) * 32 + 16 + l16] = (f16)oacc[h][1][r];
        }
    }
}

// ---------------------------------------------------------------------------
// Kernel 2b: combine split-K partials: att = (O0+O1)/(l0+l1).
// 262144 threads, each handles 8 d-elements of one (bh,q) row.
// ---------------------------------------------------------------------------
__global__ __launch_bounds__(256) void combine(
    const f16* __restrict__ po, const float* __restrict__ pl,
    f16* __restrict__ att)
{
    const int idx = blockIdx.x * 256 + threadIdx.x;   // < 262144
    const int qg  = idx >> 2;                         // bh*4096+q
    const int dg  = (idx & 3) * 8;
    const size_t sstride = (size_t)16 * NPIX * 32;    // split stride in elems

    f16x8 a = *(const f16x8*)(po + (size_t)qg * 32 + dg);
    f16x8 b = *(const f16x8*)(po + sstride + (size_t)qg * 32 + dg);
    const float inv = 1.0f / (pl[qg] + pl[qg + 16 * NPIX]);
    f16x8 o;
#pragma unroll
    for (int j = 0; j < 8; ++j)
        o[j] = (f16)(((float)a[j] + (float)b[j]) * inv);
    *(f16x8*)(att + (size_t)qg * 32 + dg) = o;
}

// ---------------------------------------------------------------------------
// Kernel 3: output projection, LDS-free MFMA GEMM, o split in halves.
// grid (64 p-tiles, 2 o-halves, 4 b) = 512 blocks.
// ---------------------------------------------------------------------------
__global__ __launch_bounds__(256) void proj_mfma(
    const f16* __restrict__ att, const f16* __restrict__ wph,
    const float* __restrict__ bp, float* __restrict__ out)
{
    const int tid  = threadIdx.x;
    const int wave = tid >> 6;
    const int lane = tid & 63;
    const int quad = lane >> 4;
    const int l16  = lane & 15;
    const int pbase = blockIdx.x * 64;
    const int obase = blockIdx.y * 64;
    const int b     = blockIdx.z;
    const int p_col = pbase + wave * 16 + l16;

    const f16* ab = att + (size_t)b * 4 * NPIX * 32;
    f16x8 bf[4];
#pragma unroll
    for (int kc = 0; kc < 4; ++kc)
        bf[kc] = *(const f16x8*)(ab + ((size_t)kc * NPIX + p_col) * 32 + quad * 8);

    floatx4 acc[4];
#pragma unroll
    for (int m = 0; m < 4; ++m) acc[m] = floatx4{0.f, 0.f, 0.f, 0.f};
#pragma unroll
    for (int m = 0; m < 4; ++m)
#pragma unroll
        for (int kc = 0; kc < 4; ++kc) {
            f16x8 af = *(const f16x8*)&wph[(size_t)(obase + m * 16 + l16) * 128 + kc * 32 + quad * 8];
            acc[m] = __builtin_amdgcn_mfma_f32_16x16x32_f16(af, bf[kc], acc[m], 0, 0, 0);
        }

#pragma unroll
    for (int m = 0; m < 4; ++m)
#pragma unroll
        for (int r = 0; r < 4; ++r) {
            const int o = obase + m * 16 + quad * 4 + r;
            out[((size_t)b * 128 + o) * NPIX + p_col] = acc[m][r] + bp[o];
        }
}

// ---------------------------------------------------------------------------
extern "C" void kernel_launch(void* const* d_in, const int* in_sizes, int n_in,
                              void* d_out, int out_size, void* d_ws, size_t ws_size,
                              hipStream_t stream)
{
    const float* x      = (const float*)d_in[0];
    const float* w_qkv  = (const float*)d_in[1];
    const float* w_proj = (const float*)d_in[2];
    const float* b_proj = (const float*)d_in[3];
    float* out = (float*)d_out;

    char* ws = (char*)d_ws;
    f16*   qh  = (f16*)(ws);                              // 4 MB [bh][p][32], pre-scaled
    f16*   kh  = (f16*)(ws + (4u << 20));                 // 4 MB [bh][p][32]
    f16*   vth = (f16*)(ws + (8u << 20));                 // 4 MB [bh][d][p]
    f16*   att = (f16*)(ws + (12u << 20));                // 4 MB [bh][p][32]
    f16*   wh  = (f16*)(ws + (16u << 20));                // 96 KB
    f16*   wph = (f16*)(ws + (16u << 20) + (96u << 10));  // 32 KB
    float* pl  = (float*)(ws + (16u << 20) + (128u << 10)); // 512 KB
    f16*   po  = (f16*)(ws + (17u << 20));                // 8.4 MB [2][bh][q][32]

    cvt_w<<<dim3(64, 1, 1), 256, 0, stream>>>(w_qkv, w_proj, wh, wph);
    qkv_mfma<<<dim3(64, 6, 4), 256, 0, stream>>>(x, wh, qh, kh, vth);
    attn_kernel<<<dim3(1024, 1, 1), 256, 0, stream>>>(qh, kh, vth, po, pl);
    combine<<<dim3(1024, 1, 1), 256, 0, stream>>>(po, pl, att);
    proj_mfma<<<dim3(64, 2, 4), 256, 0, stream>>>(att, wph, b_proj, out);
}